// Round 2
// baseline (3999.431 us; speedup 1.0000x reference)
//
#include <hip/hip_runtime.h>
#include <math.h>

// Problem constants (MultiviewCrossAttnFeature)
#define NVOX 50000
#define MV   12
#define FD   256
#define AUGD 272   // FD + 16 extrinsics
#define BQ   16384
#define HN   8
#define DKC  64
#define HD   512   // HN*DKC
#define PEO  8
#define G    4     // queries per block
#define PFS  260   // pf row stride (floats), 16B-aligned

// ---------------- min/max over voxels (N,3), fp32 ----------------
__global__ void kmm_part(const float* __restrict__ vox, float* __restrict__ part) {
    int tid = threadIdx.x;
    float mn[3] = {1e30f, 1e30f, 1e30f};
    float mx[3] = {-1e30f, -1e30f, -1e30f};
    for (int i = blockIdx.x * 256 + tid; i < NVOX; i += 64 * 256) {
        #pragma unroll
        for (int c = 0; c < 3; ++c) {
            float v = vox[3 * i + c];
            mn[c] = fminf(mn[c], v);
            mx[c] = fmaxf(mx[c], v);
        }
    }
    #pragma unroll
    for (int s = 1; s < 64; s <<= 1) {
        #pragma unroll
        for (int c = 0; c < 3; ++c) {
            mn[c] = fminf(mn[c], __shfl_xor(mn[c], s, 64));
            mx[c] = fmaxf(mx[c], __shfl_xor(mx[c], s, 64));
        }
    }
    __shared__ float smn[4][3], smx[4][3];
    int w = tid >> 6;
    if ((tid & 63) == 0) {
        #pragma unroll
        for (int c = 0; c < 3; ++c) { smn[w][c] = mn[c]; smx[w][c] = mx[c]; }
    }
    __syncthreads();
    if (tid == 0) {
        #pragma unroll
        for (int c = 0; c < 3; ++c) {
            float a = fminf(fminf(smn[0][c], smn[1][c]), fminf(smn[2][c], smn[3][c]));
            float b = fmaxf(fmaxf(smx[0][c], smx[1][c]), fmaxf(smx[2][c], smx[3][c]));
            part[blockIdx.x * 6 + c] = a;
            part[blockIdx.x * 6 + 3 + c] = b;
        }
    }
}

__global__ void kmm_final(const float* __restrict__ part, float* __restrict__ mm) {
    int t = threadIdx.x;  // 64 threads = 1 wave
    float mn[3], mx[3];
    #pragma unroll
    for (int c = 0; c < 3; ++c) { mn[c] = part[t * 6 + c]; mx[c] = part[t * 6 + 3 + c]; }
    #pragma unroll
    for (int s = 1; s < 64; s <<= 1) {
        #pragma unroll
        for (int c = 0; c < 3; ++c) {
            mn[c] = fminf(mn[c], __shfl_xor(mn[c], s, 64));
            mx[c] = fmaxf(mx[c], __shfl_xor(mx[c], s, 64));
        }
    }
    if (t == 0) {
        #pragma unroll
        for (int c = 0; c < 3; ++c) { mm[c] = mn[c]; mm[3 + c] = mx[c]; }
    }
}

// ---------------- main fused kernel: G=4 query voxels / block ----------------
// Reassociated attention, fused qW+logits (phase BC), 4 barriers total.
//   A  : stage ext/pe/mask
//   A2 : q projection (wave-local: wave w produces heads 2w, 2w+1)
//   BC : qW in registers (wave w, lane l owns t-quad l) -> logits via shfl butterfly
//   D  : softmax
//   E  : pf = p @ feat
//   F  : out = pf @ Wv
__global__ __launch_bounds__(256, 4) void kattn(
    const int* __restrict__ vi, const float* __restrict__ voxels,
    const float* __restrict__ feats, const float* __restrict__ scores,
    const int* __restrict__ cams, const float* __restrict__ extr,
    const float* __restrict__ Wq, const float* __restrict__ Wk, const float* __restrict__ Wv,
    const float* __restrict__ mm, float* __restrict__ out)
{
    // union region: pf[G][HN][PFS] (phases E,F) aliases {ext, pe, q} (phases A..BC)
    __shared__ __align__(16) float smem[G * HN * PFS];           // 33280 B
    __shared__ __align__(16) float lgt_s[G][HN][12];             // logits
    __shared__ __align__(16) float p_s[G][MV][8];                // probabilities
    __shared__ float mask_s[G][MV];

    float* pf    = smem;                                         // [G][HN][PFS]
    float* ext_s = smem;                                         // [G][MV][16] = 768 f
    float* pe_s  = smem + G * MV * 16;                           // [G][24]     = 96 f
    float* q_s   = smem + G * MV * 16 + G * 24;                  // [G][HN][64] = 2048 f
    #define EXT(g,m,e) ext_s[(((g)*MV + (m)) << 4) + (e)]
    #define QS(g,h,d)  q_s[(((g)*HN + (h)) << 6) + (d)]
    #define PFE(g,h,t) pf[((g)*HN + (h)) * PFS + (t)]

    const int tid = threadIdx.x;
    const int b0 = blockIdx.x * G;

    int idxs[G];
    #pragma unroll
    for (int g = 0; g < G; ++g) idxs[g] = vi[b0 + g];

    // ---- A: stage pe, mask, extrinsics ----
    if (tid < G * 24) {
        int g = tid / 24, t = tid % 24;
        int p = t / 3, c = t % 3;
        float vmn = mm[c], vmx = mm[3 + c];
        float x = (voxels[idxs[g] * 3 + c] - vmn) / (vmx - vmn) - 0.5f;
        pe_s[g * 24 + t] = sinf(x * (float)(1 << p));
    }
    if (tid < G * MV) {
        int g = tid / MV, m = tid % MV;
        mask_s[g][m] = (scores[idxs[g] * MV + m] < 0.0f) ? -1e30f : 0.0f;
    }
    for (int e = tid; e < G * MV * 16; e += 256) {
        int g = e / (MV * 16), r = e % (MV * 16);
        int m = r >> 4, c = r & 15;
        int cam = cams[idxs[g] * MV + m];
        EXT(g, m, c) = extr[cam * 16 + c];
    }
    __syncthreads();

    // ---- A2: Q projection. Thread tid -> head tid>>5, q cols (2c, 2c+1) ----
    {
        const float2* Wq2 = (const float2*)Wq;   // row stride 256 float2
        float2 w[24];
        #pragma unroll
        for (int t = 0; t < 24; ++t) w[t] = Wq2[t * 256 + tid];
        int h = tid >> 5, c2 = (tid & 31) * 2;
        #pragma unroll
        for (int g = 0; g < G; ++g) {
            float q0 = 0.f, q1 = 0.f;
            #pragma unroll
            for (int t = 0; t < 24; ++t) {
                float p = pe_s[g * 24 + t];
                q0 = fmaf(p, w[t].x, q0);
                q1 = fmaf(p, w[t].y, q1);
            }
            *(float2*)&QS(g, h, c2) = make_float2(q0, q1);
        }
    }
    // no barrier: wave w wrote heads {2w,2w+1}, BC of wave w reads exactly those

    // ---- BC: fused qW + logits. Wave w -> heads h0=2w, h0+1; lane l -> t-quad l ----
    {
        const int wv = tid >> 6, l = tid & 63;
        const int h0 = 2 * wv;

        // qk[hh][r][g] = qW[g][h0+hh][4l+r]
        float qk[2][4][G];
        #pragma unroll
        for (int hh = 0; hh < 2; ++hh)
            #pragma unroll
            for (int r = 0; r < 4; ++r)
                #pragma unroll
                for (int g = 0; g < G; ++g) qk[hh][r][g] = 0.f;

        const float* wkbase = Wk + (size_t)(4 * l) * HD;
        #pragma unroll
        for (int hh = 0; hh < 2; ++hh) {
            const float* wkh = wkbase + (h0 + hh) * 64;
            #pragma unroll
            for (int d8 = 0; d8 < 8; ++d8) {
                float4 qa[G], qb[G];
                #pragma unroll
                for (int g = 0; g < G; ++g) {
                    qa[g] = *(const float4*)&QS(g, h0 + hh, d8 * 8);      // broadcast
                    qb[g] = *(const float4*)&QS(g, h0 + hh, d8 * 8 + 4);
                }
                #pragma unroll
                for (int r = 0; r < 4; ++r) {
                    float4 wa = *(const float4*)(wkh + r * HD + d8 * 8);
                    float4 wb = *(const float4*)(wkh + r * HD + d8 * 8 + 4);
                    #pragma unroll
                    for (int g = 0; g < G; ++g) {
                        qk[hh][r][g] += qa[g].x * wa.x + qa[g].y * wa.y
                                      + qa[g].z * wa.z + qa[g].w * wa.w
                                      + qb[g].x * wb.x + qb[g].y * wb.y
                                      + qb[g].z * wb.z + qb[g].w * wb.w;
                    }
                }
            }
        }

        // tail rows 256..271 (extrinsics part of aug):
        // lane l = tdh*32 + thh*16 + tr handles row 256+tr, head h0+thh, d-half tdh
        const int tr  = l & 15;
        const int thh = (l >> 4) & 1;
        const int tdh = l >> 5;
        float qkt0[G], qkt1[G];
        {
            const float* wkt = Wk + (size_t)(256 + tr) * HD + (h0 + thh) * 64 + tdh * 32;
            float acc[G] = {0.f, 0.f, 0.f, 0.f};
            #pragma unroll
            for (int d8 = 0; d8 < 4; ++d8) {
                float4 wa = *(const float4*)(wkt + d8 * 8);
                float4 wb = *(const float4*)(wkt + d8 * 8 + 4);
                #pragma unroll
                for (int g = 0; g < G; ++g) {
                    float4 qa = *(const float4*)&QS(g, h0 + thh, tdh * 32 + d8 * 8);
                    float4 qb = *(const float4*)&QS(g, h0 + thh, tdh * 32 + d8 * 8 + 4);
                    acc[g] += qa.x * wa.x + qa.y * wa.y + qa.z * wa.z + qa.w * wa.w
                            + qb.x * wb.x + qb.y * wb.y + qb.z * wb.z + qb.w * wb.w;
                }
            }
            #pragma unroll
            for (int g = 0; g < G; ++g) {
                acc[g] += __shfl_xor(acc[g], 32, 64);   // combine d-halves
                // keep exactly one lane per (row, head): lanes < 32
                qkt0[g] = (l < 16) ? acc[g] : 0.f;
                qkt1[g] = (l >= 16 && l < 32) ? acc[g] : 0.f;
            }
        }

        // logits: per g, accumulate over this lane's t-quad, butterfly-reduce
        #pragma unroll
        for (int g = 0; g < G; ++g) {
            const float4* fr = (const float4*)(feats + (size_t)idxs[g] * (MV * FD));
            float part0[MV], part1[MV];
            #pragma unroll
            for (int m = 0; m < MV; ++m) {
                float4 f = fr[m * 64 + l];                       // coalesced 1KB/wave
                part0[m] = f.x * qk[0][0][g] + f.y * qk[0][1][g]
                         + f.z * qk[0][2][g] + f.w * qk[0][3][g];
                part1[m] = f.x * qk[1][0][g] + f.y * qk[1][1][g]
                         + f.z * qk[1][2][g] + f.w * qk[1][3][g];
                float e = EXT(g, m, tr);                         // 16-lane broadcast
                part0[m] = fmaf(e, qkt0[g], part0[m]);
                part1[m] = fmaf(e, qkt1[g], part1[m]);
            }
            #pragma unroll
            for (int s = 1; s < 64; s <<= 1) {
                #pragma unroll
                for (int m = 0; m < MV; ++m) {
                    part0[m] += __shfl_xor(part0[m], s, 64);
                    part1[m] += __shfl_xor(part1[m], s, 64);
                }
            }
            if (l == 0) {
                *(float4*)&lgt_s[g][h0][0] = make_float4(part0[0], part0[1], part0[2], part0[3]);
                *(float4*)&lgt_s[g][h0][4] = make_float4(part0[4], part0[5], part0[6], part0[7]);
                *(float4*)&lgt_s[g][h0][8] = make_float4(part0[8], part0[9], part0[10], part0[11]);
                *(float4*)&lgt_s[g][h0 + 1][0] = make_float4(part1[0], part1[1], part1[2], part1[3]);
                *(float4*)&lgt_s[g][h0 + 1][4] = make_float4(part1[4], part1[5], part1[6], part1[7]);
                *(float4*)&lgt_s[g][h0 + 1][8] = make_float4(part1[8], part1[9], part1[10], part1[11]);
            }
        }
    }
    __syncthreads();

    // ---- D: masked softmax over views, one (g,h) per thread ----
    if (tid < G * HN) {
        int g = tid >> 3, h = tid & 7;
        float l[MV], mx = -1e30f;
        #pragma unroll
        for (int m = 0; m < MV; ++m) {
            l[m] = lgt_s[g][h][m] * 0.125f + mask_s[g][m];
            mx = fmaxf(mx, l[m]);
        }
        float s = 0.f;
        #pragma unroll
        for (int m = 0; m < MV; ++m) { l[m] = __expf(l[m] - mx); s += l[m]; }
        float inv = 1.0f / s;
        #pragma unroll
        for (int m = 0; m < MV; ++m) p_s[g][m][h] = l[m] * inv;
    }
    __syncthreads();

    // ---- E: pf = p @ feat. Wave g; lane 'to' owns t-quad 'to' for all 8 heads ----
    {
        int g = tid >> 6, to = tid & 63;
        const float4* fr = (const float4*)(feats + (size_t)idxs[g] * (MV * FD));
        float acc[HN][4];
        #pragma unroll
        for (int h = 0; h < HN; ++h)
            #pragma unroll
            for (int r = 0; r < 4; ++r) acc[h][r] = 0.f;
        #pragma unroll 4
        for (int m = 0; m < MV; ++m) {
            float4 f  = fr[m * 64 + to];                      // coalesced
            float4 p0 = *(const float4*)&p_s[g][m][0];        // broadcast
            float4 p1 = *(const float4*)&p_s[g][m][4];
            acc[0][0] = fmaf(p0.x, f.x, acc[0][0]); acc[0][1] = fmaf(p0.x, f.y, acc[0][1]);
            acc[0][2] = fmaf(p0.x, f.z, acc[0][2]); acc[0][3] = fmaf(p0.x, f.w, acc[0][3]);
            acc[1][0] = fmaf(p0.y, f.x, acc[1][0]); acc[1][1] = fmaf(p0.y, f.y, acc[1][1]);
            acc[1][2] = fmaf(p0.y, f.z, acc[1][2]); acc[1][3] = fmaf(p0.y, f.w, acc[1][3]);
            acc[2][0] = fmaf(p0.z, f.x, acc[2][0]); acc[2][1] = fmaf(p0.z, f.y, acc[2][1]);
            acc[2][2] = fmaf(p0.z, f.z, acc[2][2]); acc[2][3] = fmaf(p0.z, f.w, acc[2][3]);
            acc[3][0] = fmaf(p0.w, f.x, acc[3][0]); acc[3][1] = fmaf(p0.w, f.y, acc[3][1]);
            acc[3][2] = fmaf(p0.w, f.z, acc[3][2]); acc[3][3] = fmaf(p0.w, f.w, acc[3][3]);
            acc[4][0] = fmaf(p1.x, f.x, acc[4][0]); acc[4][1] = fmaf(p1.x, f.y, acc[4][1]);
            acc[4][2] = fmaf(p1.x, f.z, acc[4][2]); acc[4][3] = fmaf(p1.x, f.w, acc[4][3]);
            acc[5][0] = fmaf(p1.y, f.x, acc[5][0]); acc[5][1] = fmaf(p1.y, f.y, acc[5][1]);
            acc[5][2] = fmaf(p1.y, f.z, acc[5][2]); acc[5][3] = fmaf(p1.y, f.w, acc[5][3]);
            acc[6][0] = fmaf(p1.z, f.x, acc[6][0]); acc[6][1] = fmaf(p1.z, f.y, acc[6][1]);
            acc[6][2] = fmaf(p1.z, f.z, acc[6][2]); acc[6][3] = fmaf(p1.z, f.w, acc[6][3]);
            acc[7][0] = fmaf(p1.w, f.x, acc[7][0]); acc[7][1] = fmaf(p1.w, f.y, acc[7][1]);
            acc[7][2] = fmaf(p1.w, f.z, acc[7][2]); acc[7][3] = fmaf(p1.w, f.w, acc[7][3]);
        }
        __syncthreads();   // region A (q/ext/pe) fully consumed before pf overwrite
        #pragma unroll
        for (int h = 0; h < HN; ++h)
            *(float4*)&PFE(g, h, to * 4) =
                make_float4(acc[h][0], acc[h][1], acc[h][2], acc[h][3]);
    }
    __syncthreads();

    // ---- F: out = pf @ Wv. Thread tid -> output cols (2*tid, 2*tid+1) for all g ----
    {
        const float2* Wv2 = (const float2*)Wv;   // row stride 256 float2
        int h = tid >> 5;
        float o[G][2];
        #pragma unroll
        for (int g = 0; g < G; ++g) { o[g][0] = 0.f; o[g][1] = 0.f; }
        #pragma unroll 4
        for (int t4 = 0; t4 < 64; ++t4) {
            float2 w0 = Wv2[(t4 * 4 + 0) * 256 + tid];
            float2 w1 = Wv2[(t4 * 4 + 1) * 256 + tid];
            float2 w2 = Wv2[(t4 * 4 + 2) * 256 + tid];
            float2 w3 = Wv2[(t4 * 4 + 3) * 256 + tid];
            #pragma unroll
            for (int g = 0; g < G; ++g) {
                float4 pfv = *(const float4*)&PFE(g, h, t4 * 4);  // broadcast per 32-lane group
                o[g][0] = fmaf(pfv.x, w0.x, o[g][0]); o[g][0] = fmaf(pfv.y, w1.x, o[g][0]);
                o[g][0] = fmaf(pfv.z, w2.x, o[g][0]); o[g][0] = fmaf(pfv.w, w3.x, o[g][0]);
                o[g][1] = fmaf(pfv.x, w0.y, o[g][1]); o[g][1] = fmaf(pfv.y, w1.y, o[g][1]);
                o[g][1] = fmaf(pfv.z, w2.y, o[g][1]); o[g][1] = fmaf(pfv.w, w3.y, o[g][1]);
            }
        }
        #pragma unroll
        for (int g = 0; g < G; ++g)
            ((float2*)out)[(size_t)(b0 + g) * (HD / 2) + tid] = make_float2(o[g][0], o[g][1]);
    }
}

extern "C" void kernel_launch(void* const* d_in, const int* in_sizes, int n_in,
                              void* d_out, int out_size, void* d_ws, size_t ws_size,
                              hipStream_t stream) {
    const int*   vi      = (const int*)d_in[0];
    const float* voxels  = (const float*)d_in[1];
    const float* feats   = (const float*)d_in[2];
    const float* scores  = (const float*)d_in[3];
    const int*   cams    = (const int*)d_in[4];
    const float* extr    = (const float*)d_in[5];
    const float* Wq      = (const float*)d_in[6];
    const float* Wk      = (const float*)d_in[7];
    const float* Wv      = (const float*)d_in[8];
    float* out = (float*)d_out;

    float* ws   = (float*)d_ws;
    float* mm   = ws;        // 6 floats: vmin[3], vmax[3]
    float* part = ws + 8;    // 64 * 6 partials

    kmm_part<<<64, 256, 0, stream>>>(voxels, part);
    kmm_final<<<1, 64, 0, stream>>>(part, mm);
    kattn<<<BQ / G, 256, 0, stream>>>(vi, voxels, feats, scores, cams, extr, Wq, Wk, Wv, mm, out);
}